// Round 8
// baseline (31.293 us; speedup 1.0000x reference)
//
#include <hip/hip_runtime.h>
#include <math.h>

#define WH 65536   // 256*256
#define NK 68

typedef float fvec4 __attribute__((ext_vector_type(4)));

// ---------------- Kernel 1: per-batch Procrustes solve ----------------
// Single-pass reduction: expand H = Σw(A-Ā)(B-B̄)ᵀ algebraically so all 24
// partial sums reduce in ONE 6-stage butterfly (was two dependent rounds).
__global__ __launch_bounds__(64) void solve_kernel(
    const float* __restrict__ Off, const float* __restrict__ P,
    const float* __restrict__ att, const float* __restrict__ meanp,
    const int* __restrict__ uv, float* __restrict__ RT)
{
    const int b = blockIdx.x;
    const int t = threadIdx.x;
    const float* Pb = P  + (size_t)b * 3 * WH;
    const float* Ob = Off + (size_t)b * 3 * WH;
    const float* attb = att + (size_t)b * 35 * 35;

    float src[2][3], dst[2][3], wgt[2];
    #pragma unroll
    for (int i = 0; i < 2; ++i) {
        const int k = t + 64 * i;
        const bool act = (k < NK);
        float p0=0,p1=0,p2=0,s0=0,s1=0,s2=0,w=0;
        if (act) {
            const int u0 = uv[2*k], u1 = uv[2*k+1];
            const int base = u0 * 256 + u1;
            p0 = Pb[0*WH + base];
            p1 = Pb[1*WH + base];
            p2 = Pb[2*WH + base];
            s0 = fmaf(Ob[0*WH + base], 6.0f, meanp[0*WH + base]);
            s1 = fmaf(Ob[1*WH + base], 6.0f, meanp[1*WH + base]);
            s2 = fmaf(Ob[2*WH + base], 6.0f, meanp[2*WH + base]);
            const float r0 = (u0 > 0) ? Pb[0*WH + base - 256] : 0.0f;
            const float r1 = (u0 > 0) ? Pb[1*WH + base - 256] : 0.0f;
            const float d0 = (u1 > 0) ? Pb[0*WH + base - 1]   : 0.0f;
            const float d1v= (u1 > 0) ? Pb[1*WH + base - 1]   : 0.0f;
            const float z = (p0 - r0) * (d1v - r1) - (p1 - r1) * (d0 - r0);
            const float vis = (z > 0.0f) ? 1.0f : ((z < 0.0f) ? 0.1f : z);
            int ix = (int)(p0 * 280.0f) / 8;
            int iy = (int)(p1 * 280.0f) / 8;
            ix = min(max(ix, 0), 34);
            iy = min(max(iy, 0), 34);
            w = vis * attb[iy * 35 + ix];
        }
        dst[i][0]=p0; dst[i][1]=p1; dst[i][2]=p2;
        src[i][0]=s0; src[i][1]=s1; src[i][2]=s2;
        wgt[i]=w;
    }

    // broadcast keypoint 33 (lane 33, slot 0) for d1/d2 contributions
    float s33[3], d33[3];
    #pragma unroll
    for (int c = 0; c < 3; ++c) {
        s33[c] = __shfl(src[0][c], 33);
        d33[c] = __shfl(dst[0][c], 33);
    }

    // 24 partial sums: [0..2]=SA [3..5]=SB [6]=d1 [7]=d2 [8]=Sw
    //                  [9..11]=SwA [12..14]=SwB [15..23]=SwAB (row-major i*3+j)
    float sums[24];
    #pragma unroll
    for (int j = 0; j < 24; ++j) sums[j] = 0.0f;
    #pragma unroll
    for (int i = 0; i < 2; ++i) {
        if (t + 64*i >= NK) continue;
        const float a0=src[i][0], a1=src[i][1], a2=src[i][2];
        const float b0=dst[i][0], b1=dst[i][1], b2=dst[i][2];
        const float w = wgt[i];
        sums[0]+=a0; sums[1]+=a1; sums[2]+=a2;
        sums[3]+=b0; sums[4]+=b1; sums[5]+=b2;
        const float dx0=a0-s33[0], dx1=a1-s33[1], dx2=a2-s33[2];
        const float dy0=b0-d33[0], dy1=b1-d33[1], dy2=b2-d33[2];
        sums[6] += sqrtf(dx0*dx0 + dx1*dx1 + dx2*dx2);
        sums[7] += sqrtf(dy0*dy0 + dy1*dy1 + dy2*dy2);
        sums[8] += w;
        const float wa0=w*a0, wa1=w*a1, wa2=w*a2;
        sums[9]+=wa0; sums[10]+=wa1; sums[11]+=wa2;
        sums[12]+=w*b0; sums[13]+=w*b1; sums[14]+=w*b2;
        sums[15]=fmaf(wa0,b0,sums[15]); sums[16]=fmaf(wa0,b1,sums[16]); sums[17]=fmaf(wa0,b2,sums[17]);
        sums[18]=fmaf(wa1,b0,sums[18]); sums[19]=fmaf(wa1,b1,sums[19]); sums[20]=fmaf(wa1,b2,sums[20]);
        sums[21]=fmaf(wa2,b0,sums[21]); sums[22]=fmaf(wa2,b1,sums[22]); sums[23]=fmaf(wa2,b2,sums[23]);
    }
    #pragma unroll
    for (int m = 1; m < 64; m <<= 1)
        #pragma unroll
        for (int j = 0; j < 24; ++j) sums[j] += __shfl_xor(sums[j], m);

    const float inv_nk = 1.0f / (float)NK;
    const float ms0 = sums[0]*inv_nk, ms1 = sums[1]*inv_nk, ms2 = sums[2]*inv_nk;
    const float md0 = sums[3]*inv_nk, md1 = sums[4]*inv_nk, md2 = sums[5]*inv_nk;
    const float s = sums[7] / sums[6];   // d2/d1
    const float Sw = sums[8];
    const float u0 = sums[9]  - Sw*ms0;
    const float u1 = sums[10] - Sw*ms1;
    const float u2 = sums[11] - Sw*ms2;

    // H_ij = SwAB_ij - ms_i*SwB_j - md_j*u_i
    float M[9];
    const float msv[3] = {ms0, ms1, ms2};
    const float mdv[3] = {md0, md1, md2};
    const float uv3[3] = {u0, u1, u2};
    #pragma unroll
    for (int i = 0; i < 3; ++i)
        #pragma unroll
        for (int j = 0; j < 3; ++j)
            M[i*3+j] = sums[15+i*3+j] - msv[i]*sums[12+j] - mdv[j]*uv3[i];

    // identical polar Newton on all lanes: R = V U^T = polar(M^T)
    float X[9];
    float fn = 1e-30f;
    #pragma unroll
    for (int e = 0; e < 9; ++e) fn += M[e]*M[e];
    const float rfn = 1.0f / sqrtf(fn);
    #pragma unroll
    for (int r = 0; r < 3; ++r)
        #pragma unroll
        for (int c = 0; c < 3; ++c)
            X[r*3+c] = M[c*3+r] * rfn;
    #pragma unroll
    for (int it = 0; it < 6; ++it) {
        const float C0 = X[4]*X[8]-X[5]*X[7];
        const float C1 = X[5]*X[6]-X[3]*X[8];
        const float C2 = X[3]*X[7]-X[4]*X[6];
        const float C3 = X[2]*X[7]-X[1]*X[8];
        const float C4 = X[0]*X[8]-X[2]*X[6];
        const float C5 = X[1]*X[6]-X[0]*X[7];
        const float C6 = X[1]*X[5]-X[2]*X[4];
        const float C7 = X[2]*X[3]-X[0]*X[5];
        const float C8 = X[0]*X[4]-X[1]*X[3];
        float det = X[0]*C0 + X[1]*C1 + X[2]*C2;
        if (fabsf(det) < 1e-30f) det = (det < 0.0f) ? -1e-30f : 1e-30f;
        const float g   = exp2f(-0.333333333f * log2f(fabsf(det)));  // |det|^(-1/3)
        const float idg = 1.0f / (det * g);
        X[0]=0.5f*(g*X[0]+C0*idg); X[1]=0.5f*(g*X[1]+C1*idg); X[2]=0.5f*(g*X[2]+C2*idg);
        X[3]=0.5f*(g*X[3]+C3*idg); X[4]=0.5f*(g*X[4]+C4*idg); X[5]=0.5f*(g*X[5]+C5*idg);
        X[6]=0.5f*(g*X[6]+C6*idg); X[7]=0.5f*(g*X[7]+C7*idg); X[8]=0.5f*(g*X[8]+C8*idg);
    }
    if (t == 0) {
        float* o = RT + (size_t)b * 12;
        #pragma unroll
        for (int e = 0; e < 9; ++e) o[e] = s * X[e];   // Rs
        #pragma unroll
        for (int c = 0; c < 3; ++c) {
            float acc = 0.0f;
            #pragma unroll
            for (int j = 0; j < 3; ++j) acc = fmaf(msv[j], X[c*3+j], acc);
            o[9+c] = mdv[c] - s * acc;                  // T
        }
    }
}

// ---------------- Kernel 2: fused scale + affine + transpose ----------------
__device__ __forceinline__ fvec4 aff4(fvec4 f0, fvec4 f1, fvec4 f2,
                                      float r0, float r1, float r2, float t) {
    fvec4 y;
    y.x = fmaf(f0.x, r0, fmaf(f1.x, r1, fmaf(f2.x, r2, t)));
    y.y = fmaf(f0.y, r0, fmaf(f1.y, r1, fmaf(f2.y, r2, t)));
    y.z = fmaf(f0.z, r0, fmaf(f1.z, r1, fmaf(f2.z, r2, t)));
    y.w = fmaf(f0.w, r0, fmaf(f1.w, r1, fmaf(f2.w, r2, t)));
    return y;
}

// NT loads (keep L2 clean of streaming input) + NORMAL stores (let L2
// buffer writes into coarse write-back bursts -> avoid DRAM bus turnaround).
__global__ __launch_bounds__(256) void apply_kernel(
    const float* __restrict__ Off, const float* __restrict__ meanp,
    const float* __restrict__ RT, float* __restrict__ out)
{
    const int b = blockIdx.y;
    const size_t base = (size_t)blockIdx.x * 2048 + threadIdx.x * 4;
    const size_t pA = base, pB = base + 1024;

    const float* rt = RT + (size_t)b * 12;
    const float r00=rt[0], r01=rt[1], r02=rt[2];
    const float r10=rt[3], r11=rt[4], r12=rt[5];
    const float r20=rt[6], r21=rt[7], r22=rt[8];
    const float t0=rt[9], t1=rt[10], t2=rt[11];

    const float* ob = Off + (size_t)b * 3 * WH;
    const fvec4 o0a = __builtin_nontemporal_load((const fvec4*)(ob + 0*WH + pA));
    const fvec4 o0b = __builtin_nontemporal_load((const fvec4*)(ob + 0*WH + pB));
    const fvec4 o1a = __builtin_nontemporal_load((const fvec4*)(ob + 1*WH + pA));
    const fvec4 o1b = __builtin_nontemporal_load((const fvec4*)(ob + 1*WH + pB));
    const fvec4 o2a = __builtin_nontemporal_load((const fvec4*)(ob + 2*WH + pA));
    const fvec4 o2b = __builtin_nontemporal_load((const fvec4*)(ob + 2*WH + pB));
    const fvec4 m0a = *(const fvec4*)(meanp + 0*WH + pA);
    const fvec4 m0b = *(const fvec4*)(meanp + 0*WH + pB);
    const fvec4 m1a = *(const fvec4*)(meanp + 1*WH + pA);
    const fvec4 m1b = *(const fvec4*)(meanp + 1*WH + pB);
    const fvec4 m2a = *(const fvec4*)(meanp + 2*WH + pA);
    const fvec4 m2b = *(const fvec4*)(meanp + 2*WH + pB);

    fvec4 f0a,f0b,f1a,f1b,f2a,f2b;
    f0a.x=fmaf(o0a.x,6.0f,m0a.x); f0a.y=fmaf(o0a.y,6.0f,m0a.y); f0a.z=fmaf(o0a.z,6.0f,m0a.z); f0a.w=fmaf(o0a.w,6.0f,m0a.w);
    f0b.x=fmaf(o0b.x,6.0f,m0b.x); f0b.y=fmaf(o0b.y,6.0f,m0b.y); f0b.z=fmaf(o0b.z,6.0f,m0b.z); f0b.w=fmaf(o0b.w,6.0f,m0b.w);
    f1a.x=fmaf(o1a.x,6.0f,m1a.x); f1a.y=fmaf(o1a.y,6.0f,m1a.y); f1a.z=fmaf(o1a.z,6.0f,m1a.z); f1a.w=fmaf(o1a.w,6.0f,m1a.w);
    f1b.x=fmaf(o1b.x,6.0f,m1b.x); f1b.y=fmaf(o1b.y,6.0f,m1b.y); f1b.z=fmaf(o1b.z,6.0f,m1b.z); f1b.w=fmaf(o1b.w,6.0f,m1b.w);
    f2a.x=fmaf(o2a.x,6.0f,m2a.x); f2a.y=fmaf(o2a.y,6.0f,m2a.y); f2a.z=fmaf(o2a.z,6.0f,m2a.z); f2a.w=fmaf(o2a.w,6.0f,m2a.w);
    f2b.x=fmaf(o2b.x,6.0f,m2b.x); f2b.y=fmaf(o2b.y,6.0f,m2b.y); f2b.z=fmaf(o2b.z,6.0f,m2b.z); f2b.w=fmaf(o2b.w,6.0f,m2b.w);

    float* outb = out + (size_t)b * 3 * WH;
    *(fvec4*)(outb + 0*WH + pA) = aff4(f0a,f1a,f2a,r00,r01,r02,t0);
    *(fvec4*)(outb + 0*WH + pB) = aff4(f0b,f1b,f2b,r00,r01,r02,t0);
    *(fvec4*)(outb + 1*WH + pA) = aff4(f0a,f1a,f2a,r10,r11,r12,t1);
    *(fvec4*)(outb + 1*WH + pB) = aff4(f0b,f1b,f2b,r10,r11,r12,t1);
    *(fvec4*)(outb + 2*WH + pA) = aff4(f0a,f1a,f2a,r20,r21,r22,t2);
    *(fvec4*)(outb + 2*WH + pB) = aff4(f0b,f1b,f2b,r20,r21,r22,t2);
}

extern "C" void kernel_launch(void* const* d_in, const int* in_sizes, int n_in,
                              void* d_out, int out_size, void* d_ws, size_t ws_size,
                              hipStream_t stream) {
    const float* Off   = (const float*)d_in[0];
    const float* P     = (const float*)d_in[1];
    const float* att   = (const float*)d_in[2];
    const float* meanp = (const float*)d_in[3];
    const int*   uv    = (const int*)d_in[4];
    float* out = (float*)d_out;
    float* RT  = (float*)d_ws;   // 12 floats per batch

    const int B = in_sizes[0] / (3 * WH);

    solve_kernel<<<B, 64, 0, stream>>>(Off, P, att, meanp, uv, RT);

    dim3 grid(WH / 2048, B);   // (32, B)
    apply_kernel<<<grid, 256, 0, stream>>>(Off, meanp, RT, out);
}

// Round 9
// 28.557 us; speedup vs baseline: 1.0958x; 1.0958x over previous
//
#include <hip/hip_runtime.h>
#include <math.h>

#define WH 65536   // 256*256
#define NK 68

typedef float fvec4 __attribute__((ext_vector_type(4)));

// ---------------- Kernel 1: per-batch Procrustes solve ----------------
// att table (35x35=1225 floats) is preloaded into registers FIRST so its
// HBM trip overlaps the dependent uv -> P/Off gather chain (was 2 serial
// round-trips; now max of the two).
__global__ __launch_bounds__(64) void solve_kernel(
    const float* __restrict__ Off, const float* __restrict__ P,
    const float* __restrict__ att, const float* __restrict__ meanp,
    const int* __restrict__ uv, float* __restrict__ RT)
{
    const int b = blockIdx.x;
    const int t = threadIdx.x;
    const float* Pb = P  + (size_t)b * 3 * WH;
    const float* Ob = Off + (size_t)b * 3 * WH;
    const float* attb = att + (size_t)b * 35 * 35;

    __shared__ float attLDS[1225];

    // (1) issue att loads (independent, in flight during the gather chain)
    float ra[20];
    #pragma unroll
    for (int i = 0; i < 20; ++i) {
        const int idx = t + 64 * i;
        ra[i] = (idx < 1225) ? attb[idx] : 0.0f;
    }

    // (2) dependent chain: uv -> P/Off/mean gathers
    float src[2][3], dst[2][3], vis2[2];
    int ixv[2], iyv[2];
    #pragma unroll
    for (int i = 0; i < 2; ++i) {
        const int k = t + 64 * i;
        const bool act = (k < NK);
        float p0=0,p1=0,p2=0,s0=0,s1=0,s2=0,vis=0;
        int ix=0, iy=0;
        if (act) {
            const int u0 = uv[2*k], u1 = uv[2*k+1];
            const int base = u0 * 256 + u1;
            p0 = Pb[0*WH + base];
            p1 = Pb[1*WH + base];
            p2 = Pb[2*WH + base];
            s0 = fmaf(Ob[0*WH + base], 6.0f, meanp[0*WH + base]);
            s1 = fmaf(Ob[1*WH + base], 6.0f, meanp[1*WH + base]);
            s2 = fmaf(Ob[2*WH + base], 6.0f, meanp[2*WH + base]);
            const float r0 = (u0 > 0) ? Pb[0*WH + base - 256] : 0.0f;
            const float r1 = (u0 > 0) ? Pb[1*WH + base - 256] : 0.0f;
            const float d0 = (u1 > 0) ? Pb[0*WH + base - 1]   : 0.0f;
            const float d1v= (u1 > 0) ? Pb[1*WH + base - 1]   : 0.0f;
            const float z = (p0 - r0) * (d1v - r1) - (p1 - r1) * (d0 - r0);
            vis = (z > 0.0f) ? 1.0f : ((z < 0.0f) ? 0.1f : z);
            ix = (int)(p0 * 280.0f) / 8;
            iy = (int)(p1 * 280.0f) / 8;
            ix = min(max(ix, 0), 34);
            iy = min(max(iy, 0), 34);
        }
        dst[i][0]=p0; dst[i][1]=p1; dst[i][2]=p2;
        src[i][0]=s0; src[i][1]=s1; src[i][2]=s2;
        vis2[i]=vis; ixv[i]=ix; iyv[i]=iy;
    }

    // (3) att registers -> LDS, then weight lookup from LDS
    #pragma unroll
    for (int i = 0; i < 20; ++i) {
        const int idx = t + 64 * i;
        if (idx < 1225) attLDS[idx] = ra[i];
    }
    __syncthreads();   // single wave: cheap s_barrier + lgkmcnt

    float wgt[2];
    #pragma unroll
    for (int i = 0; i < 2; ++i)
        wgt[i] = (t + 64*i < NK) ? vis2[i] * attLDS[iyv[i]*35 + ixv[i]] : 0.0f;

    // broadcast keypoint 33 (lane 33, slot 0)
    float s33[3], d33[3];
    #pragma unroll
    for (int c = 0; c < 3; ++c) {
        s33[c] = __shfl(src[0][c], 33);
        d33[c] = __shfl(dst[0][c], 33);
    }

    float sums[8];
    #pragma unroll
    for (int j = 0; j < 8; ++j) sums[j] = 0.0f;
    #pragma unroll
    for (int i = 0; i < 2; ++i) {
        if (t + 64*i >= NK) continue;
        #pragma unroll
        for (int c = 0; c < 3; ++c) { sums[c] += src[i][c]; sums[3+c] += dst[i][c]; }
        const float dx0=src[i][0]-s33[0], dx1=src[i][1]-s33[1], dx2=src[i][2]-s33[2];
        const float dy0=dst[i][0]-d33[0], dy1=dst[i][1]-d33[1], dy2=dst[i][2]-d33[2];
        sums[6] += sqrtf(dx0*dx0 + dx1*dx1 + dx2*dx2);
        sums[7] += sqrtf(dy0*dy0 + dy1*dy1 + dy2*dy2);
    }
    #pragma unroll
    for (int m = 1; m < 64; m <<= 1)
        #pragma unroll
        for (int j = 0; j < 8; ++j) sums[j] += __shfl_xor(sums[j], m);

    const float inv_nk = 1.0f / (float)NK;
    const float ms0 = sums[0]*inv_nk, ms1 = sums[1]*inv_nk, ms2 = sums[2]*inv_nk;
    const float md0 = sums[3]*inv_nk, md1 = sums[4]*inv_nk, md2 = sums[5]*inv_nk;
    const float s = sums[7] / sums[6];   // d2/d1

    float M[9];
    #pragma unroll
    for (int j = 0; j < 9; ++j) M[j] = 0.0f;
    #pragma unroll
    for (int i = 0; i < 2; ++i) {
        const float a0=src[i][0]-ms0, a1=src[i][1]-ms1, a2=src[i][2]-ms2;
        const float b0=dst[i][0]-md0, b1=dst[i][1]-md1, b2=dst[i][2]-md2;
        const float w = wgt[i];
        M[0]=fmaf(w*a0,b0,M[0]); M[1]=fmaf(w*a0,b1,M[1]); M[2]=fmaf(w*a0,b2,M[2]);
        M[3]=fmaf(w*a1,b0,M[3]); M[4]=fmaf(w*a1,b1,M[4]); M[5]=fmaf(w*a1,b2,M[5]);
        M[6]=fmaf(w*a2,b0,M[6]); M[7]=fmaf(w*a2,b1,M[7]); M[8]=fmaf(w*a2,b2,M[8]);
    }
    #pragma unroll
    for (int m = 1; m < 64; m <<= 1)
        #pragma unroll
        for (int j = 0; j < 9; ++j) M[j] += __shfl_xor(M[j], m);

    // All lanes hold M; identical polar Newton (R = V U^T = polar(M^T)).
    float X[9];
    float fn = 1e-30f;
    #pragma unroll
    for (int e = 0; e < 9; ++e) fn += M[e]*M[e];
    const float rfn = 1.0f / sqrtf(fn);
    #pragma unroll
    for (int r = 0; r < 3; ++r)
        #pragma unroll
        for (int c = 0; c < 3; ++c)
            X[r*3+c] = M[c*3+r] * rfn;
    #pragma unroll
    for (int it = 0; it < 6; ++it) {
        const float C0 = X[4]*X[8]-X[5]*X[7];
        const float C1 = X[5]*X[6]-X[3]*X[8];
        const float C2 = X[3]*X[7]-X[4]*X[6];
        const float C3 = X[2]*X[7]-X[1]*X[8];
        const float C4 = X[0]*X[8]-X[2]*X[6];
        const float C5 = X[1]*X[6]-X[0]*X[7];
        const float C6 = X[1]*X[5]-X[2]*X[4];
        const float C7 = X[2]*X[3]-X[0]*X[5];
        const float C8 = X[0]*X[4]-X[1]*X[3];
        float det = X[0]*C0 + X[1]*C1 + X[2]*C2;
        if (fabsf(det) < 1e-30f) det = (det < 0.0f) ? -1e-30f : 1e-30f;
        const float g   = exp2f(-0.333333333f * log2f(fabsf(det)));
        const float idg = 1.0f / (det * g);
        X[0]=0.5f*(g*X[0]+C0*idg); X[1]=0.5f*(g*X[1]+C1*idg); X[2]=0.5f*(g*X[2]+C2*idg);
        X[3]=0.5f*(g*X[3]+C3*idg); X[4]=0.5f*(g*X[4]+C4*idg); X[5]=0.5f*(g*X[5]+C5*idg);
        X[6]=0.5f*(g*X[6]+C6*idg); X[7]=0.5f*(g*X[7]+C7*idg); X[8]=0.5f*(g*X[8]+C8*idg);
    }
    if (t == 0) {
        float* o = RT + (size_t)b * 12;
        #pragma unroll
        for (int e = 0; e < 9; ++e) o[e] = s * X[e];   // Rs
        const float msv[3] = {ms0, ms1, ms2};
        #pragma unroll
        for (int c = 0; c < 3; ++c) {
            float acc = 0.0f;
            #pragma unroll
            for (int j = 0; j < 3; ++j) acc = fmaf(msv[j], X[c*3+j], acc);
            const float mdv = (c==0) ? md0 : ((c==1) ? md1 : md2);
            o[9+c] = mdv - s * acc;                    // T
        }
    }
}

// ---------------- Kernel 2: fused scale + affine + transpose ----------------
__device__ __forceinline__ fvec4 aff4(fvec4 f0, fvec4 f1, fvec4 f2,
                                      float r0, float r1, float r2, float t) {
    fvec4 y;
    y.x = fmaf(f0.x, r0, fmaf(f1.x, r1, fmaf(f2.x, r2, t)));
    y.y = fmaf(f0.y, r0, fmaf(f1.y, r1, fmaf(f2.y, r2, t)));
    y.z = fmaf(f0.z, r0, fmaf(f1.z, r1, fmaf(f2.z, r2, t)));
    y.w = fmaf(f0.w, r0, fmaf(f1.w, r1, fmaf(f2.w, r2, t)));
    return y;
}

// grid (32, B): two wave-contiguous 1024-float chunks per thread; NT loads
// and NT stores (best measured combination, R4/R7).
__global__ __launch_bounds__(256) void apply_kernel(
    const float* __restrict__ Off, const float* __restrict__ meanp,
    const float* __restrict__ RT, float* __restrict__ out)
{
    const int b = blockIdx.y;
    const size_t base = (size_t)blockIdx.x * 2048 + threadIdx.x * 4;
    const size_t pA = base, pB = base + 1024;

    const float* rt = RT + (size_t)b * 12;
    const float r00=rt[0], r01=rt[1], r02=rt[2];
    const float r10=rt[3], r11=rt[4], r12=rt[5];
    const float r20=rt[6], r21=rt[7], r22=rt[8];
    const float t0=rt[9], t1=rt[10], t2=rt[11];

    const float* ob = Off + (size_t)b * 3 * WH;
    const fvec4 o0a = __builtin_nontemporal_load((const fvec4*)(ob + 0*WH + pA));
    const fvec4 o0b = __builtin_nontemporal_load((const fvec4*)(ob + 0*WH + pB));
    const fvec4 o1a = __builtin_nontemporal_load((const fvec4*)(ob + 1*WH + pA));
    const fvec4 o1b = __builtin_nontemporal_load((const fvec4*)(ob + 1*WH + pB));
    const fvec4 o2a = __builtin_nontemporal_load((const fvec4*)(ob + 2*WH + pA));
    const fvec4 o2b = __builtin_nontemporal_load((const fvec4*)(ob + 2*WH + pB));
    const fvec4 m0a = *(const fvec4*)(meanp + 0*WH + pA);
    const fvec4 m0b = *(const fvec4*)(meanp + 0*WH + pB);
    const fvec4 m1a = *(const fvec4*)(meanp + 1*WH + pA);
    const fvec4 m1b = *(const fvec4*)(meanp + 1*WH + pB);
    const fvec4 m2a = *(const fvec4*)(meanp + 2*WH + pA);
    const fvec4 m2b = *(const fvec4*)(meanp + 2*WH + pB);

    fvec4 f0a,f0b,f1a,f1b,f2a,f2b;
    f0a.x=fmaf(o0a.x,6.0f,m0a.x); f0a.y=fmaf(o0a.y,6.0f,m0a.y); f0a.z=fmaf(o0a.z,6.0f,m0a.z); f0a.w=fmaf(o0a.w,6.0f,m0a.w);
    f0b.x=fmaf(o0b.x,6.0f,m0b.x); f0b.y=fmaf(o0b.y,6.0f,m0b.y); f0b.z=fmaf(o0b.z,6.0f,m0b.z); f0b.w=fmaf(o0b.w,6.0f,m0b.w);
    f1a.x=fmaf(o1a.x,6.0f,m1a.x); f1a.y=fmaf(o1a.y,6.0f,m1a.y); f1a.z=fmaf(o1a.z,6.0f,m1a.z); f1a.w=fmaf(o1a.w,6.0f,m1a.w);
    f1b.x=fmaf(o1b.x,6.0f,m1b.x); f1b.y=fmaf(o1b.y,6.0f,m1b.y); f1b.z=fmaf(o1b.z,6.0f,m1b.z); f1b.w=fmaf(o1b.w,6.0f,m1b.w);
    f2a.x=fmaf(o2a.x,6.0f,m2a.x); f2a.y=fmaf(o2a.y,6.0f,m2a.y); f2a.z=fmaf(o2a.z,6.0f,m2a.z); f2a.w=fmaf(o2a.w,6.0f,m2a.w);
    f2b.x=fmaf(o2b.x,6.0f,m2b.x); f2b.y=fmaf(o2b.y,6.0f,m2b.y); f2b.z=fmaf(o2b.z,6.0f,m2b.z); f2b.w=fmaf(o2b.w,6.0f,m2b.w);

    float* outb = out + (size_t)b * 3 * WH;
    __builtin_nontemporal_store(aff4(f0a,f1a,f2a,r00,r01,r02,t0), (fvec4*)(outb + 0*WH + pA));
    __builtin_nontemporal_store(aff4(f0b,f1b,f2b,r00,r01,r02,t0), (fvec4*)(outb + 0*WH + pB));
    __builtin_nontemporal_store(aff4(f0a,f1a,f2a,r10,r11,r12,t1), (fvec4*)(outb + 1*WH + pA));
    __builtin_nontemporal_store(aff4(f0b,f1b,f2b,r10,r11,r12,t1), (fvec4*)(outb + 1*WH + pB));
    __builtin_nontemporal_store(aff4(f0a,f1a,f2a,r20,r21,r22,t2), (fvec4*)(outb + 2*WH + pA));
    __builtin_nontemporal_store(aff4(f0b,f1b,f2b,r20,r21,r22,t2), (fvec4*)(outb + 2*WH + pB));
}

extern "C" void kernel_launch(void* const* d_in, const int* in_sizes, int n_in,
                              void* d_out, int out_size, void* d_ws, size_t ws_size,
                              hipStream_t stream) {
    const float* Off   = (const float*)d_in[0];
    const float* P     = (const float*)d_in[1];
    const float* att   = (const float*)d_in[2];
    const float* meanp = (const float*)d_in[3];
    const int*   uv    = (const int*)d_in[4];
    float* out = (float*)d_out;
    float* RT  = (float*)d_ws;   // 12 floats per batch

    const int B = in_sizes[0] / (3 * WH);

    solve_kernel<<<B, 64, 0, stream>>>(Off, P, att, meanp, uv, RT);

    dim3 grid(WH / 2048, B);   // (32, B)
    apply_kernel<<<grid, 256, 0, stream>>>(Off, meanp, RT, out);
}